// Round 7
// baseline (114.343 us; speedup 1.0000x reference)
//
#include <hip/hip_runtime.h>
#include <math.h>

namespace {
constexpr int   T_STEPS = 400;
constexpr int   HALF    = 200;            // T/2 — scan covers t = 1..200
constexpr int   NPIX    = 250 * 400;      // 100000
constexpr int   NWORDS  = 7;              // packed words cover t in [0, 224)
constexpr int   PADPIX  = 100032;         // 1563*64 — padded pixel stride
constexpr int   NSTRIPE = PADPIX / 64;    // 1563 64-pixel stripes
constexpr int   PACK_BLOCK = 256;
constexpr int   PACK_WAVES = NSTRIPE * NWORDS;                         // 10941
constexpr int   PACK_NBLK  = (PACK_WAVES + 3) / 4;                     // 4 waves/block
constexpr int   REC_BLOCK  = 64;          // one wave: no LDS, no barriers
constexpr int   REC_NBLK   = (NPIX + REC_BLOCK - 1) / REC_BLOCK;       // 1563
constexpr int   NORM_BLOCK = 256;
constexpr int   NORM_NBLK  = (NPIX + NORM_BLOCK - 1) / NORM_BLOCK;
constexpr float U0 = 0.15f;
}

// order-preserving float <-> uint key (for global atomic min/max)
__device__ __forceinline__ unsigned fkey(float f) {
  const unsigned u = __float_as_uint(f);
  return (u & 0x80000000u) ? ~u : (u | 0x80000000u);
}
__device__ __forceinline__ float funkey(unsigned k) {
  const unsigned u = (k & 0x80000000u) ? (k ^ 0x80000000u) : ~k;
  return __uint_as_float(u);
}

// ---------------- Pass 1: stream spikes -> packed bitmasks ----------------
// One wave per (64-pixel stripe, 32-timestep word). Each lane: 32 INDEPENDENT
// scalar loads (all issued before any use; ~50 VGPR -> 8 waves/SIMD, 32
// waves/CU => ~256 KB in flight per CU), then a ballot-based 32x64 bit
// transpose in registers, one coalesced 256 B store. No LDS, no barriers.
__global__ __launch_bounds__(PACK_BLOCK) void pack_spikes(
    const float* __restrict__ spikes, unsigned* __restrict__ packed) {
  const int g      = (blockIdx.x * PACK_BLOCK + threadIdx.x) >> 6;  // wave id
  const int lane   = threadIdx.x & 63;
  const int stripe = g % NSTRIPE;
  const int word   = g / NSTRIPE;
  if (word >= NWORDS) return;            // wave-uniform guard (3 excess waves)
  const int px  = stripe * 64 + lane;
  const int pxc = (px < NPIX) ? px : (NPIX - 1);   // clamp; pad region unused
  const float* __restrict__ base = spikes + (size_t)(word * 32) * NPIX + pxc;

  float v[32];
#pragma unroll
  for (int t = 0; t < 32; ++t) v[t] = base[(size_t)t * NPIX];

  unsigned b = 0u;
#pragma unroll
  for (int t = 0; t < 32; ++t) {
    const unsigned long long bal = __ballot(v[t] > 0.0f);
    b |= ((unsigned)(bal >> lane) & 1u) << t;
  }
  packed[(size_t)word * PADPIX + px] = b;
}

// ---------------- Pass 2: serial recurrence over packed bits ----------------
// Exact math (R3-verbatim): n recurrence steps with interval d.
__device__ __forceinline__ void apply_segment(float& R, float& u, int d, int n) {
  const float dd = (float)d;
  const float eD = expf(-dd);              // exp(-isi / D), D = 1
  const float eF = expf(-(dd / 10.0f));    // exp(-isi / F), F = 10
  for (int k = 0; k < n; ++k) {
    const float Rn = 1.0f - (1.0f - R * (1.0f - u)) * eD;
    const float un = U0 + (u + 0.15f * (1.0f - u) - U0) * eF;
    R = Rn; u = un;
  }
}

__device__ __forceinline__ void proc_mask(unsigned mask, int t0, int& prev,
                                          float& R, float& u, bool& done) {
  if (done) return;
  while (mask) {
    const int i = __builtin_ctz(mask);
    mask &= mask - 1u;
    const int t = t0 + i;
    if (prev >= 0) {
      const int d = t - prev;
      // t <= HALF: segment (prev, t], endpoint updates only when isi==1
      // t >  HALF: segment clipped to (prev, HALF]
      const int n = (t <= HALF) ? ((d == 1) ? 1 : (d - 1)) : (HALF - prev);
      apply_segment(R, u, d, n);
    }
    prev = t;
    if (t >= HALF) { done = true; return; }
  }
}

__global__ __launch_bounds__(REC_BLOCK) void stp_recur(
    const unsigned* __restrict__ packed, const float* __restrict__ spikes,
    float* __restrict__ img, unsigned* __restrict__ mm) {
  const int  p      = blockIdx.x * REC_BLOCK + threadIdx.x;
  const bool active = (p < NPIX);
  const int  pc     = active ? p : (NPIX - 1);

  bool  done = !active;
  int   prev = -1;
  float R = 1.0f, u = U0;

  unsigned mw[NWORDS];
#pragma unroll
  for (int w = 0; w < NWORDS; ++w) mw[w] = packed[(size_t)w * PADPIX + pc];
#pragma unroll
  for (int w = 0; w < NWORDS; ++w) proc_mask(mw[w], w * 32, prev, R, u, done);

  // Rare tail: no spike in [200,224) for some lane (P ~ 6e-8/pixel).
  // Exact fallback on raw spikes rows t >= 224.
  if (__any(done ? 0 : 1)) {
    const float* spt = spikes + pc;
    for (int t = NWORDS * 32; t < T_STEPS; ++t) {
      if (__all(done ? 1 : 0)) break;
      const float v = spt[(size_t)t * NPIX];
      if (!done && v > 0.0f) {
        if (prev >= 0) apply_segment(R, u, t - prev, HALF - prev);
        prev = t;
        done = true;            // t >= 224 > HALF
      }
    }
  }
  // Lanes never done: trailing steps have isi = inf -> no update. Exact.

  float val = 0.0f;
  if (active) {
    const float lu = logf((u - U0) / (10.0f - U0 + u * 0.85f));
    const float lR = logf((1.0f - R) / (1.0f - R * (1.0f - u)));
    val = (-1.0f / (10.0f * lu)) + (-1.0f / lR);
    img[p] = val;
  }

  // wave min/max -> one keyed atomic pair per block (no polling anywhere)
  float vmin = active ? val : INFINITY;
  float vmax = active ? val : -INFINITY;
#pragma unroll
  for (int off = 32; off > 0; off >>= 1) {
    vmin = fminf(vmin, __shfl_down(vmin, off, 64));
    vmax = fmaxf(vmax, __shfl_down(vmax, off, 64));
  }
  if (threadIdx.x == 0) {
    atomicMin(&mm[0], fkey(vmin));
    atomicMax(&mm[1], fkey(vmax));
  }
}

// ---------------- Pass 3: normalize ----------------
__global__ __launch_bounds__(NORM_BLOCK) void normalize_k(
    float* __restrict__ img, const unsigned* __restrict__ mm) {
  const int p = blockIdx.x * NORM_BLOCK + threadIdx.x;
  if (p < NPIX) {
    const float mn = funkey(mm[0]);
    const float mx = funkey(mm[1]);
    const float v  = img[p];
    img[p] = (mx != mn) ? (v - mn) / (mx - mn) : v;
  }
}

extern "C" void kernel_launch(void* const* d_in, const int* in_sizes, int n_in,
                              void* d_out, int out_size, void* d_ws, size_t ws_size,
                              hipStream_t stream) {
  const float* spikes = (const float*)d_in[0];
  float*    out    = (float*)d_out;
  unsigned* mm     = (unsigned*)d_ws;                 // [0]=min key, [1]=max key
  unsigned* packed = (unsigned*)d_ws + 64;            // 7 * PADPIX words (2.8 MB)

  // keyed min/max identity init (8 bytes, deterministic per replay)
  hipMemsetAsync(mm, 0xFF, 4, stream);                // min slot = 0xFFFFFFFF
  hipMemsetAsync(mm + 1, 0x00, 4, stream);            // max slot = 0

  hipLaunchKernelGGL(pack_spikes, dim3(PACK_NBLK), dim3(PACK_BLOCK), 0, stream,
                     spikes, packed);
  hipLaunchKernelGGL(stp_recur, dim3(REC_NBLK), dim3(REC_BLOCK), 0, stream,
                     packed, spikes, out, mm);
  hipLaunchKernelGGL(normalize_k, dim3(NORM_NBLK), dim3(NORM_BLOCK), 0, stream,
                     out, mm);
}